// Round 8
// baseline (362.254 us; speedup 1.0000x reference)
//
#include <hip/hip_runtime.h>
#include <hip/hip_fp8.h>

// ---------------------------------------------------------------------------
// Debiased Representation Loss — fused MI355X implementation (R20).
// ONE persistent kernel (512 blocks = exactly 2/CU, co-residency guaranteed
// by (256,2) + 52KB LDS), three phases separated by device-scope barriers:
//   phase 0: pre-work as static jobs per block (fz tile + softmax? + norm)
//   phase 1: R19 triangular half-pair main, atomic work queue (verbatim)
//   tail   : last 64 blocks spin for completion, then row-reduce + entropy
// Rationale: main=59us but total=169us; ~109us non-main never attributed.
// Fusing removes 2 launch gaps and measures harness overhead exactly
// (total - single_dispatch). Counters zeroed via hipMemsetAsync (capturable).
// All spins bounded (-> wrong answer, caught by absmax, instead of a hang).
// ---------------------------------------------------------------------------

#define B_N   4096
#define D_N   768
#define HID_N 256
#define NCLS  200
#define NJOBS 1056u  // 992 half-pairs + 64 half-diags
#define NBLK  512

typedef __attribute__((ext_vector_type(8))) short v8s;   // 8 x bf16 (4 VGPRs)
typedef __attribute__((ext_vector_type(4))) short v4ss;  // 4 x bf16 (8 B)
typedef __attribute__((ext_vector_type(4))) float v4f;   // MFMA accumulator

__device__ __forceinline__ unsigned short f2bf(float x) {
    unsigned int u = __float_as_uint(x);
    unsigned int r = (u + 0x7FFFu + ((u >> 16) & 1u)) >> 16;
    return (unsigned short)r;
}
__device__ __forceinline__ unsigned char f2fp8(float x) {
    __hip_fp8_e4m3 v(x);
    return (unsigned char)v.__x;
}
__device__ __forceinline__ unsigned int pack4fp8(float a, float b, float c, float d) {
    return (unsigned int)f2fp8(a) | ((unsigned int)f2fp8(b) << 8) |
           ((unsigned int)f2fp8(c) << 16) | ((unsigned int)f2fp8(d) << 24);
}
__device__ __forceinline__ void gld16c(const unsigned char* g, unsigned char* l) {
    __builtin_amdgcn_global_load_lds(
        (__attribute__((address_space(1))) void*)g,
        (__attribute__((address_space(3))) void*)l, 16, 0, 0);
}

#define ZERO_ACC24(a) { _Pragma("unroll") for (int _i = 0; _i < 2; _i++) \
    _Pragma("unroll") for (int _j = 0; _j < 4; _j++) a[_i][_j] = (v4f){0.f,0.f,0.f,0.f}; }

// bounded spin until *cnt >= want (agent scope). ~1s max, then proceed.
__device__ __forceinline__ void spin_until(int* cnt, int want) {
    int it = 0;
    while (__hip_atomic_load(cnt, __ATOMIC_ACQUIRE, __HIP_MEMORY_SCOPE_AGENT) < want) {
        __builtin_amdgcn_s_sleep(16);
        if (++it > (1 << 22)) break;     // failsafe: no container-killing hang
    }
}

// ---------------------------------------------------------------------------
// counters layout at accums (zeroed by hipMemsetAsync each launch):
//  accums[0], accums[1] : float loss sums        cbase[2] : reduce amLast
//  cbase[3] : phase-0 barrier                    cbase[4] : main job queue
//  cbase[5] : tail count
// ---------------------------------------------------------------------------
__global__ __launch_bounds__(256, 2) void fused_all(
    const float* __restrict__ z, const float* __restrict__ base,
    const float* __restrict__ w1, const float* __restrict__ w2,
    const float* __restrict__ b1, const float* __restrict__ b2,
    const float* __restrict__ logits, const int* __restrict__ oldi,
    const int* __restrict__ newi,
    unsigned char* __restrict__ zn8, unsigned char* __restrict__ bn8,
    unsigned char* __restrict__ f1z8, unsigned char* __restrict__ f2z8,
    float* __restrict__ partials, float* __restrict__ mpart,
    float* __restrict__ accums, float* __restrict__ out)
{
    __shared__ __align__(16) unsigned char S[53248];   // 52 KB, shared by phases
    __shared__ int sh_i;
    __shared__ int sh_last;
    int* cbase = (int*)accums;

    int tid = threadIdx.x, bid = blockIdx.x;
    int lane = tid & 63, wave = tid >> 6, quad = lane >> 4, col = lane & 15;

    // ======================= phase 0: pre-work =======================
    // job A: fz GEMM tile (all 512 blocks; f = bid)
    {
        unsigned short* Al = (unsigned short*)S;           // 64 x 72
        unsigned short* Bl = Al + 64 * 72;
        int f = bid;
        int which = f >> 8;                  // 0: f1, 1: f2
        int t6 = f & 255;
        int mBase = (t6 >> 2) * 64;
        int nBase = (t6 & 3) * 64;
        const float* wsrc = which ? w2 : w1;
        const float* bias = which ? b2 : b1;
        unsigned char* outz = which ? f2z8 : f1z8;
        v4f acc[4];
        #pragma unroll
        for (int i = 0; i < 4; i++) acc[i] = (v4f){0.f, 0.f, 0.f, 0.f};
        for (int kc = 0; kc < D_N; kc += 64) {
            __syncthreads();
            #pragma unroll
            for (int s = 0; s < 4; s++) {
                int slot = s * 256 + tid;
                int row = slot >> 4, k4 = slot & 15;
                float4 va = *(const float4*)(z + (size_t)(mBase + row) * D_N + kc + k4 * 4);
                float4 vb = *(const float4*)(wsrc + (size_t)(nBase + row) * D_N + kc + k4 * 4);
                v4ss sa, sb;
                sa[0] = (short)f2bf(va.x); sa[1] = (short)f2bf(va.y);
                sa[2] = (short)f2bf(va.z); sa[3] = (short)f2bf(va.w);
                sb[0] = (short)f2bf(vb.x); sb[1] = (short)f2bf(vb.y);
                sb[2] = (short)f2bf(vb.z); sb[3] = (short)f2bf(vb.w);
                *(v4ss*)(Al + row * 72 + k4 * 4) = sa;
                *(v4ss*)(Bl + row * 72 + k4 * 4) = sb;
            }
            __syncthreads();
            #pragma unroll
            for (int kk = 0; kk < 2; kk++) {
                v8s af = *(const v8s*)(Al + (wave * 16 + col) * 72 + kk * 32 + quad * 8);
                #pragma unroll
                for (int tc = 0; tc < 4; tc++) {
                    v8s bf = *(const v8s*)(Bl + (tc * 16 + col) * 72 + kk * 32 + quad * 8);
                    acc[tc] = __builtin_amdgcn_mfma_f32_16x16x32_bf16(af, bf, acc[tc], 0, 0, 0);
                }
            }
        }
        #pragma unroll
        for (int tc = 0; tc < 4; tc++) {
            int gcol = nBase + tc * 16 + col;
            float bv = bias[gcol];
            #pragma unroll
            for (int reg = 0; reg < 4; reg++) {
                int grow = mBase + wave * 16 + quad * 4 + reg;
                int sw8 = ((grow >> 3) & 1) << 3;      // half-swap key
                outz[(size_t)grow * HID_N + (gcol ^ sw8)] =
                    f2fp8(4.0f * (acc[tc][reg] + bv));
            }
        }
    }
    __syncthreads();

    // job B: softmax partials (blocks 0..255; sb = bid)
    if (bid < 256) {
        int* act = (int*)S;
        float* accs = (float*)(S + 1024);              // [4][256]
        int sb = bid;
        if (tid < NCLS) act[tid] = (tid < 100) ? oldi[tid] : newi[tid - 100];
        accs[tid] = 0.f; accs[256 + tid] = 0.f; accs[512 + tid] = 0.f; accs[768 + tid] = 0.f;
        __syncthreads();
        int a0 = act[lane], a1 = act[lane + 64], a2 = act[lane + 128];
        int a3 = (lane < 8) ? act[lane + 192] : 0;
        int r0 = sb * 16 + wave * 4;
        float c0 = 0.f, c1 = 0.f, c2 = 0.f, c3 = 0.f;
        for (int i = 0; i < 4; i++) {
            const float* lr = logits + (size_t)(r0 + i) * NCLS;
            float x0 = lr[a0], x1 = lr[a1], x2 = lr[a2];
            float x3 = (lane < 8) ? lr[a3] : -3.0e38f;
            float m = fmaxf(fmaxf(x0, x1), fmaxf(x2, x3));
            #pragma unroll
            for (int s = 32; s > 0; s >>= 1) m = fmaxf(m, __shfl_xor(m, s));
            float e0 = __expf(x0 - m), e1 = __expf(x1 - m), e2 = __expf(x2 - m);
            float e3 = (lane < 8) ? __expf(x3 - m) : 0.f;
            float sm = e0 + e1 + e2 + e3;
            #pragma unroll
            for (int s = 32; s > 0; s >>= 1) sm += __shfl_xor(sm, s);
            float inv = 1.0f / sm;
            c0 += e0 * inv; c1 += e1 * inv; c2 += e2 * inv; c3 += e3 * inv;
        }
        accs[wave * 256 + lane] = c0; accs[wave * 256 + lane + 64] = c1;
        accs[wave * 256 + lane + 128] = c2;
        if (lane < 8) accs[wave * 256 + lane + 192] = c3;
        __syncthreads();
        mpart[(size_t)tid * 256 + sb] =
            accs[tid] + accs[256 + tid] + accs[512 + tid] + accs[768 + tid];
    }
    __syncthreads();

    // job C: normalize 8 rows (nb covers 0..511 across the 512 blocks)
    {
        int nb = (bid < 256) ? (256 + bid) : (bid - 256);
        #pragma unroll
        for (int rr = 0; rr < 2; rr++) {
            int row = nb * 8 + rr * 4 + wave;
            const float* zr = z    + (size_t)row * D_N;
            const float* br = base + (size_t)row * D_N;
            float4 zv0 = *(const float4*)(zr + (size_t)lane * 4);
            float4 zv1 = *(const float4*)(zr + (size_t)(lane + 64) * 4);
            float4 zv2 = *(const float4*)(zr + (size_t)(lane + 128) * 4);
            float4 bv0 = *(const float4*)(br + (size_t)lane * 4);
            float4 bv1 = *(const float4*)(br + (size_t)(lane + 64) * 4);
            float4 bv2 = *(const float4*)(br + (size_t)(lane + 128) * 4);
            float s1 = zv0.x*zv0.x + zv0.y*zv0.y + zv0.z*zv0.z + zv0.w*zv0.w
                     + zv1.x*zv1.x + zv1.y*zv1.y + zv1.z*zv1.z + zv1.w*zv1.w
                     + zv2.x*zv2.x + zv2.y*zv2.y + zv2.z*zv2.z + zv2.w*zv2.w;
            float s2 = bv0.x*bv0.x + bv0.y*bv0.y + bv0.z*bv0.z + bv0.w*bv0.w
                     + bv1.x*bv1.x + bv1.y*bv1.y + bv1.z*bv1.z + bv1.w*bv1.w
                     + bv2.x*bv2.x + bv2.y*bv2.y + bv2.z*bv2.z + bv2.w*bv2.w;
            #pragma unroll
            for (int m = 32; m > 0; m >>= 1) {
                s1 += __shfl_xor(s1, m);
                s2 += __shfl_xor(s2, m);
            }
            float sc1 = 16.0f / fmaxf(sqrtf(s1), 1e-12f);
            float sc2 = 16.0f / fmaxf(sqrtf(s2), 1e-12f);
            size_t o = (size_t)row * D_N;
            int sw8 = ((row >> 3) & 1) << 3;         // half-swap key
            *(unsigned int*)(zn8 + o + (((lane      ) * 4) ^ sw8)) =
                pack4fp8(zv0.x*sc1, zv0.y*sc1, zv0.z*sc1, zv0.w*sc1);
            *(unsigned int*)(zn8 + o + (((lane +  64) * 4) ^ sw8)) =
                pack4fp8(zv1.x*sc1, zv1.y*sc1, zv1.z*sc1, zv1.w*sc1);
            *(unsigned int*)(zn8 + o + (((lane + 128) * 4) ^ sw8)) =
                pack4fp8(zv2.x*sc1, zv2.y*sc1, zv2.z*sc1, zv2.w*sc1);
            *(unsigned int*)(bn8 + o + (((lane      ) * 4) ^ sw8)) =
                pack4fp8(bv0.x*sc2, bv0.y*sc2, bv0.z*sc2, bv0.w*sc2);
            *(unsigned int*)(bn8 + o + (((lane +  64) * 4) ^ sw8)) =
                pack4fp8(bv1.x*sc2, bv1.y*sc2, bv1.z*sc2, bv1.w*sc2);
            *(unsigned int*)(bn8 + o + (((lane + 128) * 4) ^ sw8)) =
                pack4fp8(bv2.x*sc2, bv2.y*sc2, bv2.z*sc2, bv2.w*sc2);
        }
    }

    // ======================= barrier A (device) =======================
    __threadfence();
    __syncthreads();
    if (tid == 0) {
        __hip_atomic_fetch_add(&cbase[3], 1, __ATOMIC_ACQ_REL, __HIP_MEMORY_SCOPE_AGENT);
        spin_until(&cbase[3], NBLK);
    }
    __syncthreads();
    __threadfence();

    // ======================= phase 1: main (R19 verbatim) =============
    {
        unsigned char* SA_B = S;
        unsigned char* SA_S = S + 8192;
        unsigned char* SB_B = S + 16384;
        unsigned char* SB_S = S + 32768;
        unsigned char* F1   = S;
        unsigned char* F2   = S + 16384;
        float4* red = (float4*)(S + 49152);            // [2][128]
        int wr3 = wave >> 1, wc3 = wave & 1;
        const int r8 = lane >> 3;
        const int kbl8 = (lane & 7) ^ r8;
        const int sub8 = ((quad & 1) ^ (col >> 3)) << 3;

        for (;;) {
            __syncthreads();                           // LDS + sh_i reuse guard
            if (tid == 0) sh_i = atomicAdd(&cbase[4], 1);
            __syncthreads();
            unsigned int j = (unsigned int)sh_i;
            if (j >= NJOBS) break;

            int ib, jc, h; bool diag;
            if (j < 992u) {
                int pp = (int)(j >> 1); h = (int)(j & 1u); diag = false;
                int t = (int)((1.0f + sqrtf(8.0f * (float)pp + 1.0f)) * 0.5f);
                t = (t < 1) ? 1 : ((t > 31) ? 31 : t);
                while (t > 1  && t * (t - 1) / 2 > pp) --t;
                while (t < 31 && (t + 1) * t / 2 <= pp) ++t;
                jc = t; ib = pp - t * (t - 1) / 2;     // 0 <= ib < jc < 32
            } else {
                int dd = (int)(j - 992u); ib = jc = dd >> 1; h = dd & 1; diag = true;
            }
            int aRow0 = ib * 128 + h * 64;
            int bRow0 = jc * 128;

            v4f accB[2][4], accS[2][4];
            ZERO_ACC24(accB); ZERO_ACC24(accS);
            for (int kc = 0; kc < D_N; kc += 128) {
                __syncthreads();
                #pragma unroll
                for (int s = 0; s < 4; s++) {
                    int rowbase = s * 32 + wave * 8;
                    size_t gOff = (size_t)(bRow0 + rowbase + r8) * D_N + kc + kbl8 * 16;
                    gld16c(bn8 + gOff, SB_B + rowbase * 128);
                    gld16c(zn8 + gOff, SB_S + rowbase * 128);
                }
                if (!diag) {
                    #pragma unroll
                    for (int s = 0; s < 2; s++) {
                        int rowbase = s * 32 + wave * 8;
                        size_t gOff = (size_t)(aRow0 + rowbase + r8) * D_N + kc + kbl8 * 16;
                        gld16c(bn8 + gOff, SA_B + rowbase * 128);
                        gld16c(zn8 + gOff, SA_S + rowbase * 128);
                    }
                }
                __syncthreads();
                const unsigned char* AB = diag ? (SB_B + h * 64 * 128) : SA_B;
                const unsigned char* AS = diag ? (SB_S + h * 64 * 128) : SA_S;
                #pragma unroll
                for (int kk = 0; kk < 4; kk++) {
                    int gbase = kk * 2 + (quad >> 1);
                    int off = ((gbase ^ (col & 7)) << 4) + sub8;
                    long a1[2], a2[2], b1[4], b2[4];
                    #pragma unroll
                    for (int t = 0; t < 2; t++) {
                        int rA = (wr3 * 32 + t * 16 + col) * 128;
                        a1[t] = *(const long*)(AB + rA + off);
                        a2[t] = *(const long*)(AS + rA + off);
                    }
                    #pragma unroll
                    for (int t = 0; t < 4; t++) {
                        int rB = (wc3 * 64 + t * 16 + col) * 128;
                        b1[t] = *(const long*)(SB_B + rB + off);
                        b2[t] = *(const long*)(SB_S + rB + off);
                    }
                    #pragma unroll
                    for (int tr = 0; tr < 2; tr++)
                        #pragma unroll
                        for (int tc = 0; tc < 4; tc++) {
                            accB[tr][tc] = __builtin_amdgcn_mfma_f32_16x16x32_fp8_fp8(
                                a1[tr], b1[tc], accB[tr][tc], 0, 0, 0);
                            accS[tr][tc] = __builtin_amdgcn_mfma_f32_16x16x32_fp8_fp8(
                                a2[tr], b2[tc], accS[tr][tc], 0, 0, 0);
                        }
                }
            }

            __syncthreads();              // MS LDS reads complete
            {
                int r4 = lane >> 4;
                #pragma unroll
                for (int s = 0; s < 8; s++) {
                    int rowbase = s * 16 + wave * 4;
                    int row = rowbase + r4;
                    int kb = (lane & 15) ^ (row & 15);
                    gld16c(f2z8 + (size_t)(bRow0 + row) * HID_N + kb * 16, F2 + rowbase * 256);
                }
                #pragma unroll
                for (int s = 0; s < 4; s++) {
                    int rowbase = s * 16 + wave * 4;
                    int row = rowbase + r4;
                    int kb = (lane & 15) ^ (row & 15);
                    gld16c(f1z8 + (size_t)(aRow0 + row) * HID_N + kb * 16, F1 + rowbase * 256);
                }
            }

            unsigned int mb = 0u;
            #pragma unroll
            for (int tr = 0; tr < 2; tr++)
                #pragma unroll
                for (int tc = 0; tc < 4; tc++)
                    #pragma unroll
                    for (int reg = 0; reg < 4; reg++) {
                        int grow = aRow0 + wr3 * 32 + tr * 16 + quad * 4 + reg;
                        int gcol = bRow0 + wc3 * 64 + tc * 16 + col;
                        if (accB[tr][tc][reg] > 12.8f && grow != gcol)
                            mb |= 1u << (tr * 16 + tc * 4 + reg);
                    }

            v4f accA[2][4]; ZERO_ACC24(accA);
            __syncthreads();              // DMA drained
            #pragma unroll
            for (int kk = 0; kk < 8; kk++) {
                int gbase = kk * 2 + (quad >> 1);
                int off = ((gbase ^ col) << 4) + sub8;
                long af[2], bf[4];
                #pragma unroll
                for (int t = 0; t < 2; t++)
                    af[t] = *(const long*)(F1 + (wr3 * 32 + t * 16 + col) * 256 + off);
                #pragma unroll
                for (int t = 0; t < 4; t++)
                    bf[t] = *(const long*)(F2 + (wc3 * 64 + t * 16 + col) * 256 + off);
                #pragma unroll
                for (int tr = 0; tr < 2; tr++)
                    #pragma unroll
                    for (int tc = 0; tc < 4; tc++)
                        accA[tr][tc] = __builtin_amdgcn_mfma_f32_16x16x32_fp8_fp8(
                            af[tr], bf[tc], accA[tr][tc], 0, 0, 0);
            }

            __syncthreads();
            if (!diag) {
                int r4 = lane >> 4;
                #pragma unroll
                for (int s = 0; s < 8; s++) {
                    int rowbase = s * 16 + wave * 4;
                    int row = rowbase + r4;
                    int kb = (lane & 15) ^ (row & 15);
                    gld16c(f1z8 + (size_t)(bRow0 + row) * HID_N + kb * 16, F2 + rowbase * 256);
                }
                #pragma unroll
                for (int s = 0; s < 4; s++) {
                    int rowbase = s * 16 + wave * 4;
                    int row = rowbase + r4;
                    int kb = (lane & 15) ^ (row & 15);
                    gld16c(f2z8 + (size_t)(aRow0 + row) * HID_N + kb * 16, F1 + rowbase * 256);
                }
            }

            // combine orient-1 (rows in A), streaming per tr
            #pragma unroll
            for (int tr = 0; tr < 2; tr++) {
                float ls[4], as[4], nn[4], ds[4];
                #pragma unroll
                for (int r = 0; r < 4; r++) { ls[r]=0.f; as[r]=0.f; nn[r]=0.f; ds[r]=0.f; }
                #pragma unroll
                for (int tc = 0; tc < 4; tc++)
                    #pragma unroll
                    for (int reg = 0; reg < 4; reg++) {
                        float sv = accS[tr][tc][reg] * 0.00390625f;
                        int grow = aRow0 + wr3 * 32 + tr * 16 + quad * 4 + reg;
                        int gcol = bRow0 + wc3 * 64 + tc * 16 + col;
                        if (grow != gcol) ds[reg] += __expf(sv * 10.0f);
                        if ((mb >> (tr * 16 + tc * 4 + reg)) & 1u) {
                            float e = __expf(accA[tr][tc][reg] * 0.0625f);
                            ls[reg] += e; as[reg] += e * sv; nn[reg] += 1.f;
                        }
                    }
                #pragma unroll
                for (int r = 0; r < 4; r++) {
                    #pragma unroll
                    for (int m = 1; m < 16; m <<= 1) {
                        ls[r] += __shfl_xor(ls[r], m);
                        as[r] += __shfl_xor(as[r], m);
                        ds[r] += __shfl_xor(ds[r], m);
                        nn[r] += __shfl_xor(nn[r], m);
                    }
                    if (col == 0) {
                        int row = aRow0 + wr3 * 32 + tr * 16 + quad * 4 + r;
                        float4 v; v.x = ls[r]; v.y = as[r]; v.z = ds[r]; v.w = nn[r];
                        *(float4*)(partials + ((size_t)row * 64 + jc * 2 + wc3) * 4) = v;
                    }
                }
            }

            // attn pass 2 + combine orient-2 (rows in C), pairs only
            if (!diag) {
                ZERO_ACC24(accA);
                __syncthreads();          // pass-2 DMA drained
                #pragma unroll
                for (int kk = 0; kk < 8; kk++) {
                    int gbase = kk * 2 + (quad >> 1);
                    int off = ((gbase ^ col) << 4) + sub8;
                    long af[2], bf[4];
                    #pragma unroll
                    for (int t = 0; t < 2; t++)
                        af[t] = *(const long*)(F1 + (wr3 * 32 + t * 16 + col) * 256 + off);
                    #pragma unroll
                    for (int t = 0; t < 4; t++)
                        bf[t] = *(const long*)(F2 + (wc3 * 64 + t * 16 + col) * 256 + off);
                    #pragma unroll
                    for (int tr = 0; tr < 2; tr++)
                        #pragma unroll
                        for (int tc = 0; tc < 4; tc++)
                            accA[tr][tc] = __builtin_amdgcn_mfma_f32_16x16x32_fp8_fp8(
                                af[tr], bf[tc], accA[tr][tc], 0, 0, 0);
                }
                #pragma unroll
                for (int tc = 0; tc < 4; tc++) {
                    float l2 = 0.f, a2 = 0.f, d2 = 0.f, n2 = 0.f;
                    #pragma unroll
                    for (int tr = 0; tr < 2; tr++)
                        #pragma unroll
                        for (int reg = 0; reg < 4; reg++) {
                            float sv = accS[tr][tc][reg] * 0.00390625f;
                            d2 += __expf(sv * 10.0f);
                            if ((mb >> (tr * 16 + tc * 4 + reg)) & 1u) {
                                float e = __expf(accA[tr][tc][reg] * 0.0625f);
                                l2 += e; a2 += e * sv; n2 += 1.f;
                            }
                        }
                    #pragma unroll
                    for (int m = 16; m < 64; m <<= 1) {
                        l2 += __shfl_xor(l2, m);
                        a2 += __shfl_xor(a2, m);
                        d2 += __shfl_xor(d2, m);
                        n2 += __shfl_xor(n2, m);
                    }
                    if (lane < 16) {
                        float4 v; v.x = l2; v.y = a2; v.z = d2; v.w = n2;
                        red[wr3 * 128 + wc3 * 64 + tc * 16 + lane] = v;
                    }
                }
                __syncthreads();          // red complete
                if (tid < 128) {
                    float4 u = red[tid], v = red[128 + tid];
                    float4 w; w.x = u.x + v.x; w.y = u.y + v.y;
                    w.z = u.z + v.z; w.w = u.w + v.w;
                    *(float4*)(partials + ((size_t)(bRow0 + tid) * 64 + ib * 2 + h) * 4) = w;
                }
            }
        }
    }

    // ======================= tail: row-reduce + entropy ===============
    __threadfence();
    __syncthreads();
    if (tid == 0)
        sh_i = __hip_atomic_fetch_add(&cbase[5], 1, __ATOMIC_ACQ_REL, __HIP_MEMORY_SCOPE_AGENT);
    __syncthreads();
    int myslot = sh_i;
    if (myslot < NBLK - 64) return;       // only last 64 blocks reduce
    if (tid == 0) spin_until(&cbase[5], NBLK);
    __syncthreads();
    __threadfence();
    int slot = myslot - (NBLK - 64);      // 0..63

    {
        float* rr_red = (float*)S;                    // 1 KB
        float* rr_r2s = (float*)(S + 1024);           // 1 KB
        float* rr_bc  = (float*)(S + 2048);           // 2 floats

        int row = slot * 64 + (tid >> 2);
        int sub = tid & 3;
        const float4* p = (const float4*)partials + (size_t)row * 64 + sub * 16;
        float L = 0.f, A = 0.f, Dn = 0.f, NN = 0.f;
        #pragma unroll
        for (int c = 0; c < 16; c++) { float4 v = p[c]; L += v.x; A += v.y; Dn += v.z; NN += v.w; }
        #pragma unroll
        for (int m = 1; m < 4; m <<= 1) {
            L += __shfl_xor(L, m); A += __shfl_xor(A, m);
            Dn += __shfl_xor(Dn, m); NN += __shfl_xor(NN, m);
        }
        float per = 0.f, val = 0.f;
        if (sub == 0 && NN > 0.5f) {
            per = (logf(Dn + 1e-8f) - 10.0f * (A / L)) / NN;
            val = 1.0f;
        }
        rr_red[tid] = per; rr_r2s[tid] = val; __syncthreads();
        for (int s = 128; s > 0; s >>= 1) {
            if (tid < s) { rr_red[tid] += rr_red[tid + s]; rr_r2s[tid] += rr_r2s[tid + s]; }
            __syncthreads();
        }
        if (tid == 0) {
            atomicAdd(&accums[0], rr_red[0]);
            atomicAdd(&accums[1], rr_r2s[0]);
            __threadfence();
            int old = atomicAdd(&cbase[2], 1);
            sh_last = (old == 63);
        }
        __syncthreads();
        if (!sh_last) return;

        float pcl = 0.0f;
        if (tid < NCLS) {
            const float4* mp = (const float4*)(mpart + (size_t)tid * 256);
            float s = 0.f;
            #pragma unroll
            for (int c = 0; c < 64; c++) { float4 v = mp[c]; s += v.x + v.y + v.z + v.w; }
            pcl = s * (1.0f / 4096.0f);
        }
        rr_red[tid] = (tid < 100) ? pcl : 0.0f; __syncthreads();
        for (int s = 128; s > 0; s >>= 1) { if (tid < s) rr_red[tid] += rr_red[tid + s]; __syncthreads(); }
        if (tid == 0) rr_bc[0] = rr_red[0];
        __syncthreads();
        rr_red[tid] = (tid >= 100 && tid < NCLS) ? pcl : 0.0f; __syncthreads();
        for (int s = 128; s > 0; s >>= 1) { if (tid < s) rr_red[tid] += rr_red[tid + s]; __syncthreads(); }
        if (tid == 0) rr_bc[1] = rr_red[0];
        __syncthreads();
        float p_old = rr_bc[0], p_new = rr_bc[1];

        float t = 0.0f;
        if (tid < 100)       { float q = pcl / (p_old + 1e-8f); t = q * logf(q + 1e-8f); }
        else if (tid < NCLS) { float q = pcl / (p_new + 1e-8f); t = q * logf(q + 1e-8f); }
        rr_red[tid] = t; __syncthreads();
        for (int s = 128; s > 0; s >>= 1) { if (tid < s) rr_red[tid] += rr_red[tid + s]; __syncthreads(); }

        if (tid == 0) {
            float s0 = __hip_atomic_load(&accums[0], __ATOMIC_RELAXED, __HIP_MEMORY_SCOPE_AGENT);
            float s1 = __hip_atomic_load(&accums[1], __ATOMIC_RELAXED, __HIP_MEMORY_SCOPE_AGENT);
            float loss_inter = p_old * logf(p_old + 1e-8f) + p_new * logf(p_new + 1e-8f)
                               + 0.69314718056f;
            float loss_entropy = loss_inter + rr_red[0] + 2.0f * 4.60517018599f;
            float lc = (s1 > 0.5f) ? s0 / s1 : 0.0f;
            out[0] = loss_entropy + lc;
        }
    }
}

// ---------------------------------------------------------------------------
extern "C" void kernel_launch(void* const* d_in, const int* in_sizes, int n_in,
                              void* d_out, int out_size, void* d_ws, size_t ws_size,
                              hipStream_t stream)
{
    const float* z_u    = (const float*)d_in[0];
    const float* logits = (const float*)d_in[1];
    const int*   oldi   = (const int*)d_in[2];
    const int*   newi   = (const int*)d_in[3];
    const float* basef  = (const float*)d_in[4];
    const float* f1w    = (const float*)d_in[5];
    const float* f1b    = (const float*)d_in[6];
    const float* f2w    = (const float*)d_in[7];
    const float* f2b    = (const float*)d_in[8];
    float* out = (float*)d_out;

    unsigned char* zn8   = (unsigned char*)d_ws;           // [B][D] fp8
    unsigned char* bn8   = zn8 + (size_t)B_N * D_N;
    unsigned char* f1z8  = bn8 + (size_t)B_N * D_N;        // [B][HID] fp8
    unsigned char* f2z8  = f1z8 + (size_t)B_N * HID_N;
    float* partials = (float*)(f2z8 + (size_t)B_N * HID_N); // [B][64][4]
    float* mpart    = partials + (size_t)B_N * 64 * 4;      // [256 class][256 blk]
    float* accums   = mpart + 256 * 256;                    // sums + counters

    hipMemsetAsync(accums, 0, 32, stream);
    fused_all<<<NBLK, 256, 0, stream>>>(
        z_u, basef, f1w, f2w, f1b, f2b, logits, oldi, newi,
        zn8, bn8, f1z8, f2z8, partials, mpart, accums, out);
}

// Round 9
// 233.696 us; speedup vs baseline: 1.5501x; 1.5501x over previous
//
#include <hip/hip_runtime.h>
#include <hip/hip_fp8.h>

// ---------------------------------------------------------------------------
// Debiased Representation Loss — fused MI355X implementation (R21).
// R20 single persistent kernel + MINIMAL-FENCE device barriers.
// R20 post-mortem: work ran at full speed (MFMA/VALU-equivalents match the
// 3-kernel sum) but ~190us was pure waiting — per-WAVE __threadfence at the
// barriers emits buffer_wbl2/buffer_inv (full per-XCD L2 writeback/inv,
// ~8K chip-wide cache sweeps).  R21 fence plan (derived from line ownership):
//  * barrier A: writer-side wbl2 ONCE per block (after __syncthreads drains
//    stores to L2); NO reader inv — phase-0 output lines are single-writer,
//    fully written, never previously cached by reader XCDs.
//  * tail: writer wbl2 once per block; reducers do ONE inv after the spin
//    (their L2 may hold stale clean copies of partials lines).
//  * spins use RELAXED atomic loads (no per-poll cache ops).
// Attribution banked from R20: fixed harness overhead = total-dispatch = 37us.
// ---------------------------------------------------------------------------

#define B_N   4096
#define D_N   768
#define HID_N 256
#define NCLS  200
#define NJOBS 1056u  // 992 half-pairs + 64 half-diags
#define NBLK  512

typedef __attribute__((ext_vector_type(8))) short v8s;   // 8 x bf16 (4 VGPRs)
typedef __attribute__((ext_vector_type(4))) short v4ss;  // 4 x bf16 (8 B)
typedef __attribute__((ext_vector_type(4))) float v4f;   // MFMA accumulator

__device__ __forceinline__ unsigned short f2bf(float x) {
    unsigned int u = __float_as_uint(x);
    unsigned int r = (u + 0x7FFFu + ((u >> 16) & 1u)) >> 16;
    return (unsigned short)r;
}
__device__ __forceinline__ unsigned char f2fp8(float x) {
    __hip_fp8_e4m3 v(x);
    return (unsigned char)v.__x;
}
__device__ __forceinline__ unsigned int pack4fp8(float a, float b, float c, float d) {
    return (unsigned int)f2fp8(a) | ((unsigned int)f2fp8(b) << 8) |
           ((unsigned int)f2fp8(c) << 16) | ((unsigned int)f2fp8(d) << 24);
}
__device__ __forceinline__ void gld16c(const unsigned char* g, unsigned char* l) {
    __builtin_amdgcn_global_load_lds(
        (__attribute__((address_space(1))) void*)g,
        (__attribute__((address_space(3))) void*)l, 16, 0, 0);
}

#define ZERO_ACC24(a) { _Pragma("unroll") for (int _i = 0; _i < 2; _i++) \
    _Pragma("unroll") for (int _j = 0; _j < 4; _j++) a[_i][_j] = (v4f){0.f,0.f,0.f,0.f}; }

// bounded spin until *cnt >= want. RELAXED polls (no cache-maintenance ops).
__device__ __forceinline__ void spin_relaxed(int* cnt, int want) {
    int it = 0;
    while (__hip_atomic_load(cnt, __ATOMIC_RELAXED, __HIP_MEMORY_SCOPE_AGENT) < want) {
        __builtin_amdgcn_s_sleep(16);
        if (++it > (1 << 22)) break;     // failsafe: no container-killing hang
    }
}

// ---------------------------------------------------------------------------
// counters at accums (hipMemsetAsync-zeroed): [0],[1] float loss sums;
// cbase[2] reduce-last; cbase[3] phase-0 barrier; cbase[4] job queue;
// cbase[5] tail count.
// ---------------------------------------------------------------------------
__global__ __launch_bounds__(256, 2) void fused_all(
    const float* __restrict__ z, const float* __restrict__ base,
    const float* __restrict__ w1, const float* __restrict__ w2,
    const float* __restrict__ b1, const float* __restrict__ b2,
    const float* __restrict__ logits, const int* __restrict__ oldi,
    const int* __restrict__ newi,
    unsigned char* __restrict__ zn8, unsigned char* __restrict__ bn8,
    unsigned char* __restrict__ f1z8, unsigned char* __restrict__ f2z8,
    float* __restrict__ partials, float* __restrict__ mpart,
    float* __restrict__ accums, float* __restrict__ out)
{
    __shared__ __align__(16) unsigned char S[53248];   // 52 KB, shared by phases
    __shared__ int sh_i;
    __shared__ int sh_last;
    int* cbase = (int*)accums;

    int tid = threadIdx.x, bid = blockIdx.x;
    int lane = tid & 63, wave = tid >> 6, quad = lane >> 4, col = lane & 15;

    // ======================= phase 0: pre-work =======================
    // job A: fz GEMM tile (all 512 blocks; f = bid)
    {
        unsigned short* Al = (unsigned short*)S;           // 64 x 72
        unsigned short* Bl = Al + 64 * 72;
        int f = bid;
        int which = f >> 8;                  // 0: f1, 1: f2
        int t6 = f & 255;
        int mBase = (t6 >> 2) * 64;
        int nBase = (t6 & 3) * 64;
        const float* wsrc = which ? w2 : w1;
        const float* bias = which ? b2 : b1;
        unsigned char* outz = which ? f2z8 : f1z8;
        v4f acc[4];
        #pragma unroll
        for (int i = 0; i < 4; i++) acc[i] = (v4f){0.f, 0.f, 0.f, 0.f};
        for (int kc = 0; kc < D_N; kc += 64) {
            __syncthreads();
            #pragma unroll
            for (int s = 0; s < 4; s++) {
                int slot = s * 256 + tid;
                int row = slot >> 4, k4 = slot & 15;
                float4 va = *(const float4*)(z + (size_t)(mBase + row) * D_N + kc + k4 * 4);
                float4 vb = *(const float4*)(wsrc + (size_t)(nBase + row) * D_N + kc + k4 * 4);
                v4ss sa, sb;
                sa[0] = (short)f2bf(va.x); sa[1] = (short)f2bf(va.y);
                sa[2] = (short)f2bf(va.z); sa[3] = (short)f2bf(va.w);
                sb[0] = (short)f2bf(vb.x); sb[1] = (short)f2bf(vb.y);
                sb[2] = (short)f2bf(vb.z); sb[3] = (short)f2bf(vb.w);
                *(v4ss*)(Al + row * 72 + k4 * 4) = sa;
                *(v4ss*)(Bl + row * 72 + k4 * 4) = sb;
            }
            __syncthreads();
            #pragma unroll
            for (int kk = 0; kk < 2; kk++) {
                v8s af = *(const v8s*)(Al + (wave * 16 + col) * 72 + kk * 32 + quad * 8);
                #pragma unroll
                for (int tc = 0; tc < 4; tc++) {
                    v8s bf = *(const v8s*)(Bl + (tc * 16 + col) * 72 + kk * 32 + quad * 8);
                    acc[tc] = __builtin_amdgcn_mfma_f32_16x16x32_bf16(af, bf, acc[tc], 0, 0, 0);
                }
            }
        }
        #pragma unroll
        for (int tc = 0; tc < 4; tc++) {
            int gcol = nBase + tc * 16 + col;
            float bv = bias[gcol];
            #pragma unroll
            for (int reg = 0; reg < 4; reg++) {
                int grow = mBase + wave * 16 + quad * 4 + reg;
                int sw8 = ((grow >> 3) & 1) << 3;      // half-swap key
                outz[(size_t)grow * HID_N + (gcol ^ sw8)] =
                    f2fp8(4.0f * (acc[tc][reg] + bv));
            }
        }
    }
    __syncthreads();

    // job B: softmax partials (blocks 0..255; sb = bid)
    if (bid < 256) {
        int* act = (int*)S;
        float* accs = (float*)(S + 1024);              // [4][256]
        int sb = bid;
        if (tid < NCLS) act[tid] = (tid < 100) ? oldi[tid] : newi[tid - 100];
        accs[tid] = 0.f; accs[256 + tid] = 0.f; accs[512 + tid] = 0.f; accs[768 + tid] = 0.f;
        __syncthreads();
        int a0 = act[lane], a1 = act[lane + 64], a2 = act[lane + 128];
        int a3 = (lane < 8) ? act[lane + 192] : 0;
        int r0 = sb * 16 + wave * 4;
        float c0 = 0.f, c1 = 0.f, c2 = 0.f, c3 = 0.f;
        for (int i = 0; i < 4; i++) {
            const float* lr = logits + (size_t)(r0 + i) * NCLS;
            float x0 = lr[a0], x1 = lr[a1], x2 = lr[a2];
            float x3 = (lane < 8) ? lr[a3] : -3.0e38f;
            float m = fmaxf(fmaxf(x0, x1), fmaxf(x2, x3));
            #pragma unroll
            for (int s = 32; s > 0; s >>= 1) m = fmaxf(m, __shfl_xor(m, s));
            float e0 = __expf(x0 - m), e1 = __expf(x1 - m), e2 = __expf(x2 - m);
            float e3 = (lane < 8) ? __expf(x3 - m) : 0.f;
            float sm = e0 + e1 + e2 + e3;
            #pragma unroll
            for (int s = 32; s > 0; s >>= 1) sm += __shfl_xor(sm, s);
            float inv = 1.0f / sm;
            c0 += e0 * inv; c1 += e1 * inv; c2 += e2 * inv; c3 += e3 * inv;
        }
        accs[wave * 256 + lane] = c0; accs[wave * 256 + lane + 64] = c1;
        accs[wave * 256 + lane + 128] = c2;
        if (lane < 8) accs[wave * 256 + lane + 192] = c3;
        __syncthreads();
        mpart[(size_t)tid * 256 + sb] =
            accs[tid] + accs[256 + tid] + accs[512 + tid] + accs[768 + tid];
    }
    __syncthreads();

    // job C: normalize 8 rows (nb covers 0..511 across the 512 blocks)
    {
        int nb = (bid < 256) ? (256 + bid) : (bid - 256);
        #pragma unroll
        for (int rr = 0; rr < 2; rr++) {
            int row = nb * 8 + rr * 4 + wave;
            const float* zr = z    + (size_t)row * D_N;
            const float* br = base + (size_t)row * D_N;
            float4 zv0 = *(const float4*)(zr + (size_t)lane * 4);
            float4 zv1 = *(const float4*)(zr + (size_t)(lane + 64) * 4);
            float4 zv2 = *(const float4*)(zr + (size_t)(lane + 128) * 4);
            float4 bv0 = *(const float4*)(br + (size_t)lane * 4);
            float4 bv1 = *(const float4*)(br + (size_t)(lane + 64) * 4);
            float4 bv2 = *(const float4*)(br + (size_t)(lane + 128) * 4);
            float s1 = zv0.x*zv0.x + zv0.y*zv0.y + zv0.z*zv0.z + zv0.w*zv0.w
                     + zv1.x*zv1.x + zv1.y*zv1.y + zv1.z*zv1.z + zv1.w*zv1.w
                     + zv2.x*zv2.x + zv2.y*zv2.y + zv2.z*zv2.z + zv2.w*zv2.w;
            float s2 = bv0.x*bv0.x + bv0.y*bv0.y + bv0.z*bv0.z + bv0.w*bv0.w
                     + bv1.x*bv1.x + bv1.y*bv1.y + bv1.z*bv1.z + bv1.w*bv1.w
                     + bv2.x*bv2.x + bv2.y*bv2.y + bv2.z*bv2.z + bv2.w*bv2.w;
            #pragma unroll
            for (int m = 32; m > 0; m >>= 1) {
                s1 += __shfl_xor(s1, m);
                s2 += __shfl_xor(s2, m);
            }
            float sc1 = 16.0f / fmaxf(sqrtf(s1), 1e-12f);
            float sc2 = 16.0f / fmaxf(sqrtf(s2), 1e-12f);
            size_t o = (size_t)row * D_N;
            int sw8 = ((row >> 3) & 1) << 3;         // half-swap key
            *(unsigned int*)(zn8 + o + (((lane      ) * 4) ^ sw8)) =
                pack4fp8(zv0.x*sc1, zv0.y*sc1, zv0.z*sc1, zv0.w*sc1);
            *(unsigned int*)(zn8 + o + (((lane +  64) * 4) ^ sw8)) =
                pack4fp8(zv1.x*sc1, zv1.y*sc1, zv1.z*sc1, zv1.w*sc1);
            *(unsigned int*)(zn8 + o + (((lane + 128) * 4) ^ sw8)) =
                pack4fp8(zv2.x*sc1, zv2.y*sc1, zv2.z*sc1, zv2.w*sc1);
            *(unsigned int*)(bn8 + o + (((lane      ) * 4) ^ sw8)) =
                pack4fp8(bv0.x*sc2, bv0.y*sc2, bv0.z*sc2, bv0.w*sc2);
            *(unsigned int*)(bn8 + o + (((lane +  64) * 4) ^ sw8)) =
                pack4fp8(bv1.x*sc2, bv1.y*sc2, bv1.z*sc2, bv1.w*sc2);
            *(unsigned int*)(bn8 + o + (((lane + 128) * 4) ^ sw8)) =
                pack4fp8(bv2.x*sc2, bv2.y*sc2, bv2.z*sc2, bv2.w*sc2);
        }
    }

    // ============ barrier A: writer-release only, once per block ============
    __syncthreads();                      // drains all waves' stores to L2
    if (tid == 0) {
        __threadfence();                  // ONE wbl2 per block (writer release)
        __hip_atomic_fetch_add(&cbase[3], 1, __ATOMIC_RELAXED, __HIP_MEMORY_SCOPE_AGENT);
        spin_relaxed(&cbase[3], NBLK);
    }
    __syncthreads();
    // no reader-side inv: phase-0 output lines were never cached by readers

    // ======================= phase 1: main (R19 verbatim) =============
    {
        unsigned char* SA_B = S;
        unsigned char* SA_S = S + 8192;
        unsigned char* SB_B = S + 16384;
        unsigned char* SB_S = S + 32768;
        unsigned char* F1   = S;
        unsigned char* F2   = S + 16384;
        float4* red = (float4*)(S + 49152);            // [2][128]
        int wr3 = wave >> 1, wc3 = wave & 1;
        const int r8 = lane >> 3;
        const int kbl8 = (lane & 7) ^ r8;
        const int sub8 = ((quad & 1) ^ (col >> 3)) << 3;

        for (;;) {
            __syncthreads();                           // LDS + sh_i reuse guard
            if (tid == 0) sh_i = atomicAdd(&cbase[4], 1);
            __syncthreads();
            unsigned int j = (unsigned int)sh_i;
            if (j >= NJOBS) break;

            int ib, jc, h; bool diag;
            if (j < 992u) {
                int pp = (int)(j >> 1); h = (int)(j & 1u); diag = false;
                int t = (int)((1.0f + sqrtf(8.0f * (float)pp + 1.0f)) * 0.5f);
                t = (t < 1) ? 1 : ((t > 31) ? 31 : t);
                while (t > 1  && t * (t - 1) / 2 > pp) --t;
                while (t < 31 && (t + 1) * t / 2 <= pp) ++t;
                jc = t; ib = pp - t * (t - 1) / 2;     // 0 <= ib < jc < 32
            } else {
                int dd = (int)(j - 992u); ib = jc = dd >> 1; h = dd & 1; diag = true;
            }
            int aRow0 = ib * 128 + h * 64;
            int bRow0 = jc * 128;

            v4f accB[2][4], accS[2][4];
            ZERO_ACC24(accB); ZERO_ACC24(accS);
            for (int kc = 0; kc < D_N; kc += 128) {
                __syncthreads();
                #pragma unroll
                for (int s = 0; s < 4; s++) {
                    int rowbase = s * 32 + wave * 8;
                    size_t gOff = (size_t)(bRow0 + rowbase + r8) * D_N + kc + kbl8 * 16;
                    gld16c(bn8 + gOff, SB_B + rowbase * 128);
                    gld16c(zn8 + gOff, SB_S + rowbase * 128);
                }
                if (!diag) {
                    #pragma unroll
                    for (int s = 0; s < 2; s++) {
                        int rowbase = s * 32 + wave * 8;
                        size_t gOff = (size_t)(aRow0 + rowbase + r8) * D_N + kc + kbl8 * 16;
                        gld16c(bn8 + gOff, SA_B + rowbase * 128);
                        gld16c(zn8 + gOff, SA_S + rowbase * 128);
                    }
                }
                __syncthreads();
                const unsigned char* AB = diag ? (SB_B + h * 64 * 128) : SA_B;
                const unsigned char* AS = diag ? (SB_S + h * 64 * 128) : SA_S;
                #pragma unroll
                for (int kk = 0; kk < 4; kk++) {
                    int gbase = kk * 2 + (quad >> 1);
                    int off = ((gbase ^ (col & 7)) << 4) + sub8;
                    long a1[2], a2[2], b1[4], b2[4];
                    #pragma unroll
                    for (int t = 0; t < 2; t++) {
                        int rA = (wr3 * 32 + t * 16 + col) * 128;
                        a1[t] = *(const long*)(AB + rA + off);
                        a2[t] = *(const long*)(AS + rA + off);
                    }
                    #pragma unroll
                    for (int t = 0; t < 4; t++) {
                        int rB = (wc3 * 64 + t * 16 + col) * 128;
                        b1[t] = *(const long*)(SB_B + rB + off);
                        b2[t] = *(const long*)(SB_S + rB + off);
                    }
                    #pragma unroll
                    for (int tr = 0; tr < 2; tr++)
                        #pragma unroll
                        for (int tc = 0; tc < 4; tc++) {
                            accB[tr][tc] = __builtin_amdgcn_mfma_f32_16x16x32_fp8_fp8(
                                a1[tr], b1[tc], accB[tr][tc], 0, 0, 0);
                            accS[tr][tc] = __builtin_amdgcn_mfma_f32_16x16x32_fp8_fp8(
                                a2[tr], b2[tc], accS[tr][tc], 0, 0, 0);
                        }
                }
            }

            __syncthreads();              // MS LDS reads complete
            {
                int r4 = lane >> 4;
                #pragma unroll
                for (int s = 0; s < 8; s++) {
                    int rowbase = s * 16 + wave * 4;
                    int row = rowbase + r4;
                    int kb = (lane & 15) ^ (row & 15);
                    gld16c(f2z8 + (size_t)(bRow0 + row) * HID_N + kb * 16, F2 + rowbase * 256);
                }
                #pragma unroll
                for (int s = 0; s < 4; s++) {
                    int rowbase = s * 16 + wave * 4;
                    int row = rowbase + r4;
                    int kb = (lane & 15) ^ (row & 15);
                    gld16c(f1z8 + (size_t)(aRow0 + row) * HID_N + kb * 16, F1 + rowbase * 256);
                }
            }

            unsigned int mb = 0u;
            #pragma unroll
            for (int tr = 0; tr < 2; tr++)
                #pragma unroll
                for (int tc = 0; tc < 4; tc++)
                    #pragma unroll
                    for (int reg = 0; reg < 4; reg++) {
                        int grow = aRow0 + wr3 * 32 + tr * 16 + quad * 4 + reg;
                        int gcol = bRow0 + wc3 * 64 + tc * 16 + col;
                        if (accB[tr][tc][reg] > 12.8f && grow != gcol)
                            mb |= 1u << (tr * 16 + tc * 4 + reg);
                    }

            v4f accA[2][4]; ZERO_ACC24(accA);
            __syncthreads();              // DMA drained
            #pragma unroll
            for (int kk = 0; kk < 8; kk++) {
                int gbase = kk * 2 + (quad >> 1);
                int off = ((gbase ^ col) << 4) + sub8;
                long af[2], bf[4];
                #pragma unroll
                for (int t = 0; t < 2; t++)
                    af[t] = *(const long*)(F1 + (wr3 * 32 + t * 16 + col) * 256 + off);
                #pragma unroll
                for (int t = 0; t < 4; t++)
                    bf[t] = *(const long*)(F2 + (wc3 * 64 + t * 16 + col) * 256 + off);
                #pragma unroll
                for (int tr = 0; tr < 2; tr++)
                    #pragma unroll
                    for (int tc = 0; tc < 4; tc++)
                        accA[tr][tc] = __builtin_amdgcn_mfma_f32_16x16x32_fp8_fp8(
                            af[tr], bf[tc], accA[tr][tc], 0, 0, 0);
            }

            __syncthreads();
            if (!diag) {
                int r4 = lane >> 4;
                #pragma unroll
                for (int s = 0; s < 8; s++) {
                    int rowbase = s * 16 + wave * 4;
                    int row = rowbase + r4;
                    int kb = (lane & 15) ^ (row & 15);
                    gld16c(f1z8 + (size_t)(bRow0 + row) * HID_N + kb * 16, F2 + rowbase * 256);
                }
                #pragma unroll
                for (int s = 0; s < 4; s++) {
                    int rowbase = s * 16 + wave * 4;
                    int row = rowbase + r4;
                    int kb = (lane & 15) ^ (row & 15);
                    gld16c(f2z8 + (size_t)(aRow0 + row) * HID_N + kb * 16, F1 + rowbase * 256);
                }
            }

            // combine orient-1 (rows in A), streaming per tr
            #pragma unroll
            for (int tr = 0; tr < 2; tr++) {
                float ls[4], as[4], nn[4], ds[4];
                #pragma unroll
                for (int r = 0; r < 4; r++) { ls[r]=0.f; as[r]=0.f; nn[r]=0.f; ds[r]=0.f; }
                #pragma unroll
                for (int tc = 0; tc < 4; tc++)
                    #pragma unroll
                    for (int reg = 0; reg < 4; reg++) {
                        float sv = accS[tr][tc][reg] * 0.00390625f;
                        int grow = aRow0 + wr3 * 32 + tr * 16 + quad * 4 + reg;
                        int gcol = bRow0 + wc3 * 64 + tc * 16 + col;
                        if (grow != gcol) ds[reg] += __expf(sv * 10.0f);
                        if ((mb >> (tr * 16 + tc * 4 + reg)) & 1u) {
                            float e = __expf(accA[tr][tc][reg] * 0.0625f);
                            ls[reg] += e; as[reg] += e * sv; nn[reg] += 1.f;
                        }
                    }
                #pragma unroll
                for (int r = 0; r < 4; r++) {
                    #pragma unroll
                    for (int m = 1; m < 16; m <<= 1) {
                        ls[r] += __shfl_xor(ls[r], m);
                        as[r] += __shfl_xor(as[r], m);
                        ds[r] += __shfl_xor(ds[r], m);
                        nn[r] += __shfl_xor(nn[r], m);
                    }
                    if (col == 0) {
                        int row = aRow0 + wr3 * 32 + tr * 16 + quad * 4 + r;
                        float4 v; v.x = ls[r]; v.y = as[r]; v.z = ds[r]; v.w = nn[r];
                        *(float4*)(partials + ((size_t)row * 64 + jc * 2 + wc3) * 4) = v;
                    }
                }
            }

            // attn pass 2 + combine orient-2 (rows in C), pairs only
            if (!diag) {
                ZERO_ACC24(accA);
                __syncthreads();          // pass-2 DMA drained
                #pragma unroll
                for (int kk = 0; kk < 8; kk++) {
                    int gbase = kk * 2 + (quad >> 1);
                    int off = ((gbase ^ col) << 4) + sub8;
                    long af[2], bf[4];
                    #pragma unroll
                    for (int t = 0; t < 2; t++)
                        af[t] = *(const long*)(F1 + (wr3 * 32 + t * 16 + col) * 256 + off);
                    #pragma unroll
                    for (int t = 0; t < 4; t++)
                        bf[t] = *(const long*)(F2 + (wc3 * 64 + t * 16 + col) * 256 + off);
                    #pragma unroll
                    for (int tr = 0; tr < 2; tr++)
                        #pragma unroll
                        for (int tc = 0; tc < 4; tc++)
                            accA[tr][tc] = __builtin_amdgcn_mfma_f32_16x16x32_fp8_fp8(
                                af[tr], bf[tc], accA[tr][tc], 0, 0, 0);
                }
                #pragma unroll
                for (int tc = 0; tc < 4; tc++) {
                    float l2 = 0.f, a2 = 0.f, d2 = 0.f, n2 = 0.f;
                    #pragma unroll
                    for (int tr = 0; tr < 2; tr++)
                        #pragma unroll
                        for (int reg = 0; reg < 4; reg++) {
                            float sv = accS[tr][tc][reg] * 0.00390625f;
                            d2 += __expf(sv * 10.0f);
                            if ((mb >> (tr * 16 + tc * 4 + reg)) & 1u) {
                                float e = __expf(accA[tr][tc][reg] * 0.0625f);
                                l2 += e; a2 += e * sv; n2 += 1.f;
                            }
                        }
                    #pragma unroll
                    for (int m = 16; m < 64; m <<= 1) {
                        l2 += __shfl_xor(l2, m);
                        a2 += __shfl_xor(a2, m);
                        d2 += __shfl_xor(d2, m);
                        n2 += __shfl_xor(n2, m);
                    }
                    if (lane < 16) {
                        float4 v; v.x = l2; v.y = a2; v.z = d2; v.w = n2;
                        red[wr3 * 128 + wc3 * 64 + tc * 16 + lane] = v;
                    }
                }
                __syncthreads();          // red complete
                if (tid < 128) {
                    float4 u = red[tid], v = red[128 + tid];
                    float4 w; w.x = u.x + v.x; w.y = u.y + v.y;
                    w.z = u.z + v.z; w.w = u.w + v.w;
                    *(float4*)(partials + ((size_t)(bRow0 + tid) * 64 + ib * 2 + h) * 4) = w;
                }
            }
        }
    }

    // ============ tail: writer release once, reducers inv once ==============
    __syncthreads();                      // drains this block's partials stores
    if (tid == 0) {
        __threadfence();                  // ONE wbl2 per block
        sh_i = __hip_atomic_fetch_add(&cbase[5], 1, __ATOMIC_RELAXED, __HIP_MEMORY_SCOPE_AGENT);
    }
    __syncthreads();
    int myslot = sh_i;
    if (myslot < NBLK - 64) return;       // only last 64 blocks reduce
    if (tid == 0) {
        spin_relaxed(&cbase[5], NBLK);
        __threadfence();                  // inv: discard stale clean copies
    }
    __syncthreads();
    int slot = myslot - (NBLK - 64);      // 0..63

    {
        float* rr_red = (float*)S;                    // 1 KB
        float* rr_r2s = (float*)(S + 1024);           // 1 KB
        float* rr_bc  = (float*)(S + 2048);           // 2 floats

        int row = slot * 64 + (tid >> 2);
        int sub = tid & 3;
        const float4* p = (const float4*)partials + (size_t)row * 64 + sub * 16;
        float L = 0.f, A = 0.f, Dn = 0.f, NN = 0.f;
        #pragma unroll
        for (int c = 0; c < 16; c++) { float4 v = p[c]; L += v.x; A += v.y; Dn += v.z; NN += v.w; }
        #pragma unroll
        for (int m = 1; m < 4; m <<= 1) {
            L += __shfl_xor(L, m); A += __shfl_xor(A, m);
            Dn += __shfl_xor(Dn, m); NN += __shfl_xor(NN, m);
        }
        float per = 0.f, val = 0.f;
        if (sub == 0 && NN > 0.5f) {
            per = (logf(Dn + 1e-8f) - 10.0f * (A / L)) / NN;
            val = 1.0f;
        }
        rr_red[tid] = per; rr_r2s[tid] = val; __syncthreads();
        for (int s = 128; s > 0; s >>= 1) {
            if (tid < s) { rr_red[tid] += rr_red[tid + s]; rr_r2s[tid] += rr_r2s[tid + s]; }
            __syncthreads();
        }
        if (tid == 0) {
            atomicAdd(&accums[0], rr_red[0]);
            atomicAdd(&accums[1], rr_r2s[0]);
            __threadfence();
            int old = atomicAdd(&cbase[2], 1);
            sh_last = (old == 63);
        }
        __syncthreads();
        if (!sh_last) return;

        float pcl = 0.0f;
        if (tid < NCLS) {
            const float4* mp = (const float4*)(mpart + (size_t)tid * 256);
            float s = 0.f;
            #pragma unroll
            for (int c = 0; c < 64; c++) { float4 v = mp[c]; s += v.x + v.y + v.z + v.w; }
            pcl = s * (1.0f / 4096.0f);
        }
        rr_red[tid] = (tid < 100) ? pcl : 0.0f; __syncthreads();
        for (int s = 128; s > 0; s >>= 1) { if (tid < s) rr_red[tid] += rr_red[tid + s]; __syncthreads(); }
        if (tid == 0) rr_bc[0] = rr_red[0];
        __syncthreads();
        rr_red[tid] = (tid >= 100 && tid < NCLS) ? pcl : 0.0f; __syncthreads();
        for (int s = 128; s > 0; s >>= 1) { if (tid < s) rr_red[tid] += rr_red[tid + s]; __syncthreads(); }
        if (tid == 0) rr_bc[1] = rr_red[0];
        __syncthreads();
        float p_old = rr_bc[0], p_new = rr_bc[1];

        float t = 0.0f;
        if (tid < 100)       { float q = pcl / (p_old + 1e-8f); t = q * logf(q + 1e-8f); }
        else if (tid < NCLS) { float q = pcl / (p_new + 1e-8f); t = q * logf(q + 1e-8f); }
        rr_red[tid] = t; __syncthreads();
        for (int s = 128; s > 0; s >>= 1) { if (tid < s) rr_red[tid] += rr_red[tid + s]; __syncthreads(); }

        if (tid == 0) {
            float s0 = __hip_atomic_load(&accums[0], __ATOMIC_RELAXED, __HIP_MEMORY_SCOPE_AGENT);
            float s1 = __hip_atomic_load(&accums[1], __ATOMIC_RELAXED, __HIP_MEMORY_SCOPE_AGENT);
            float loss_inter = p_old * logf(p_old + 1e-8f) + p_new * logf(p_new + 1e-8f)
                               + 0.69314718056f;
            float loss_entropy = loss_inter + rr_red[0] + 2.0f * 4.60517018599f;
            float lc = (s1 > 0.5f) ? s0 / s1 : 0.0f;
            out[0] = loss_entropy + lc;
        }
    }
}

// ---------------------------------------------------------------------------
extern "C" void kernel_launch(void* const* d_in, const int* in_sizes, int n_in,
                              void* d_out, int out_size, void* d_ws, size_t ws_size,
                              hipStream_t stream)
{
    const float* z_u    = (const float*)d_in[0];
    const float* logits = (const float*)d_in[1];
    const int*   oldi   = (const int*)d_in[2];
    const int*   newi   = (const int*)d_in[3];
    const float* basef  = (const float*)d_in[4];
    const float* f1w    = (const float*)d_in[5];
    const float* f1b    = (const float*)d_in[6];
    const float* f2w    = (const float*)d_in[7];
    const float* f2b    = (const float*)d_in[8];
    float* out = (float*)d_out;

    unsigned char* zn8   = (unsigned char*)d_ws;           // [B][D] fp8
    unsigned char* bn8   = zn8 + (size_t)B_N * D_N;
    unsigned char* f1z8  = bn8 + (size_t)B_N * D_N;        // [B][HID] fp8
    unsigned char* f2z8  = f1z8 + (size_t)B_N * HID_N;
    float* partials = (float*)(f2z8 + (size_t)B_N * HID_N); // [B][64][4]
    float* mpart    = partials + (size_t)B_N * 64 * 4;      // [256 class][256 blk]
    float* accums   = mpart + 256 * 256;                    // sums + counters

    hipMemsetAsync(accums, 0, 32, stream);
    fused_all<<<NBLK, 256, 0, stream>>>(
        z_u, basef, f1w, f2w, f1b, f2b, logits, oldi, newi,
        zn8, bn8, f1z8, f2z8, partials, mpart, accums, out);
}

// Round 10
// 164.637 us; speedup vs baseline: 2.2003x; 1.4195x over previous
//
#include <hip/hip_runtime.h>
#include <hip/hip_fp8.h>

// ---------------------------------------------------------------------------
// Debiased Representation Loss — fused MI355X implementation (R22).
// R19 3-kernel structure VERBATIM (168.7us known-good; main 59.4us) +
// pre_all fz staging conversion cheapened:
//   RNE f2bf (4-5 VALU ops/elem) -> TRUNCATION pack, 2 floats -> 1 u32 via
//   (hi & 0xFFFF0000) | (lo >> 16)  (3 ops per PAIR).  fz is VALU-bound
//   (only ~14MB of HBM traffic), conversion was ~1700 ops/thread.
//   Truncation error (<=0.4%) is below the fp8 quantization already applied
//   to fz's output and the whole mask/sim path.
// R20/R21 lessons banked: persistent fusion runs pre-work at 1/4 occupancy
// (net loss); per-wave __threadfence at device barriers costs ~190us in
// L2 writeback/inv storms; fixed harness overhead ~= 37us (total-dispatch).
// ---------------------------------------------------------------------------

#define B_N   4096
#define D_N   768
#define HID_N 256
#define NCLS  200
#define NJOBS 1056u  // 992 half-pairs + 64 half-diags

typedef __attribute__((ext_vector_type(8))) short v8s;   // 8 x bf16 (4 VGPRs)
typedef __attribute__((ext_vector_type(4))) float v4f;   // MFMA accumulator

// fp32 -> OCP e4m3 (RNE, saturating)
__device__ __forceinline__ unsigned char f2fp8(float x) {
    __hip_fp8_e4m3 v(x);
    return (unsigned char)v.__x;
}
// pack 4 floats -> 4 fp8 bytes in a u32
__device__ __forceinline__ unsigned int pack4fp8(float a, float b, float c, float d) {
    return (unsigned int)f2fp8(a) | ((unsigned int)f2fp8(b) << 8) |
           ((unsigned int)f2fp8(c) << 16) | ((unsigned int)f2fp8(d) << 24);
}
// two floats -> packed 2 x bf16 (truncation; hi in high half)
__device__ __forceinline__ unsigned int pk2bf_trunc(float lo, float hi) {
    return (__float_as_uint(hi) & 0xFFFF0000u) | (__float_as_uint(lo) >> 16);
}

// async global->LDS, 16 B per lane
__device__ __forceinline__ void gld16c(const unsigned char* g, unsigned char* l) {
    __builtin_amdgcn_global_load_lds(
        (__attribute__((address_space(1))) void*)g,
        (__attribute__((address_space(3))) void*)l, 16, 0, 0);
}

#define ZERO_ACC24(a) { _Pragma("unroll") for (int _i = 0; _i < 2; _i++) \
    _Pragma("unroll") for (int _j = 0; _j < 4; _j++) a[_i][_j] = (v4f){0.f,0.f,0.f,0.f}; }

// ---------------------------------------------------------------------------
// Kernel 1: pre_all — three independent block families, heavy-first order.
//  [0,512)     : fz = z@W^T+b, 64x64 tiles, f32 in (trunc-pack bf16), fp8 out
//  [512,768)   : softmax partials (sb==0 zeroes accums, incl. job counter)
//  [768,1280)  : L2-normalize 8 rows/block -> zn8/bn8 fp8 (x16, half-swap)
// ---------------------------------------------------------------------------
__global__ __launch_bounds__(256) void pre_all(
    const float* __restrict__ z, const float* __restrict__ base,
    const float* __restrict__ w1, const float* __restrict__ w2,
    const float* __restrict__ b1, const float* __restrict__ b2,
    const float* __restrict__ logits, const int* __restrict__ oldi,
    const int* __restrict__ newi,
    unsigned char* __restrict__ zn8, unsigned char* __restrict__ bn8,
    unsigned char* __restrict__ f1z8, unsigned char* __restrict__ f2z8,
    float* __restrict__ mpart, float* __restrict__ accums)
{
    __shared__ __align__(16) unsigned char shmem[2 * 64 * 72 * 2];  // 18.4 KB
    int tid = threadIdx.x;

    if (blockIdx.x < 512) {
        // ---- fz GEMM: 512 blocks, 64x64 tiles, K=768 ----
        unsigned short* Al = (unsigned short*)shmem;           // 64 x 72
        unsigned short* Bl = Al + 64 * 72;
        int f = blockIdx.x;
        int which = f >> 8;                  // 0: f1, 1: f2
        int t6 = f & 255;
        int mBase = (t6 >> 2) * 64;
        int nBase = (t6 & 3) * 64;
        const float* wsrc = which ? w2 : w1;
        const float* bias = which ? b2 : b1;
        unsigned char* outz = which ? f2z8 : f1z8;
        int lane = tid & 63, wave = tid >> 6, quad = lane >> 4, col = lane & 15;
        v4f acc[4];
        #pragma unroll
        for (int i = 0; i < 4; i++) acc[i] = (v4f){0.f, 0.f, 0.f, 0.f};
        for (int kc = 0; kc < D_N; kc += 64) {
            __syncthreads();
            #pragma unroll
            for (int s = 0; s < 4; s++) {
                int slot = s * 256 + tid;
                int row = slot >> 4, k4 = slot & 15;
                float4 va = *(const float4*)(z + (size_t)(mBase + row) * D_N + kc + k4 * 4);
                float4 vb = *(const float4*)(wsrc + (size_t)(nBase + row) * D_N + kc + k4 * 4);
                uint2 ua, ub;
                ua.x = pk2bf_trunc(va.x, va.y); ua.y = pk2bf_trunc(va.z, va.w);
                ub.x = pk2bf_trunc(vb.x, vb.y); ub.y = pk2bf_trunc(vb.z, vb.w);
                *(uint2*)(Al + row * 72 + k4 * 4) = ua;   // 8B aligned (144-byte rows)
                *(uint2*)(Bl + row * 72 + k4 * 4) = ub;
            }
            __syncthreads();
            #pragma unroll
            for (int kk = 0; kk < 2; kk++) {
                v8s af = *(const v8s*)(Al + (wave * 16 + col) * 72 + kk * 32 + quad * 8);
                #pragma unroll
                for (int tc = 0; tc < 4; tc++) {
                    v8s bf = *(const v8s*)(Bl + (tc * 16 + col) * 72 + kk * 32 + quad * 8);
                    acc[tc] = __builtin_amdgcn_mfma_f32_16x16x32_bf16(af, bf, acc[tc], 0, 0, 0);
                }
            }
        }
        #pragma unroll
        for (int tc = 0; tc < 4; tc++) {
            int gcol = nBase + tc * 16 + col;
            float bv = bias[gcol];
            #pragma unroll
            for (int reg = 0; reg < 4; reg++) {
                int grow = mBase + wave * 16 + quad * 4 + reg;
                int sw8 = ((grow >> 3) & 1) << 3;      // half-swap key
                outz[(size_t)grow * HID_N + (gcol ^ sw8)] =
                    f2fp8(4.0f * (acc[tc][reg] + bv));
            }
        }
        return;
    }
    if (blockIdx.x < 768) {
        // ---- softmax partials: 256 blocks x 16 rows ----
        int* act = (int*)shmem;
        float* accs = (float*)(shmem + 1024);          // [4][256]
        int sb = blockIdx.x - 512;
        int lane = tid & 63, wave = tid >> 6;
        if (sb == 0 && tid < 6) accums[tid] = 0.0f;    // [4] = main job counter
        if (tid < NCLS) act[tid] = (tid < 100) ? oldi[tid] : newi[tid - 100];
        accs[tid] = 0.f; accs[256 + tid] = 0.f; accs[512 + tid] = 0.f; accs[768 + tid] = 0.f;
        __syncthreads();
        int a0 = act[lane], a1 = act[lane + 64], a2 = act[lane + 128];
        int a3 = (lane < 8) ? act[lane + 192] : 0;
        int r0 = sb * 16 + wave * 4;
        float c0 = 0.f, c1 = 0.f, c2 = 0.f, c3 = 0.f;
        for (int i = 0; i < 4; i++) {
            const float* lr = logits + (size_t)(r0 + i) * NCLS;
            float x0 = lr[a0], x1 = lr[a1], x2 = lr[a2];
            float x3 = (lane < 8) ? lr[a3] : -3.0e38f;
            float m = fmaxf(fmaxf(x0, x1), fmaxf(x2, x3));
            #pragma unroll
            for (int s = 32; s > 0; s >>= 1) m = fmaxf(m, __shfl_xor(m, s));
            float e0 = __expf(x0 - m), e1 = __expf(x1 - m), e2 = __expf(x2 - m);
            float e3 = (lane < 8) ? __expf(x3 - m) : 0.f;
            float sm = e0 + e1 + e2 + e3;
            #pragma unroll
            for (int s = 32; s > 0; s >>= 1) sm += __shfl_xor(sm, s);
            float inv = 1.0f / sm;
            c0 += e0 * inv; c1 += e1 * inv; c2 += e2 * inv; c3 += e3 * inv;
        }
        accs[wave * 256 + lane] = c0; accs[wave * 256 + lane + 64] = c1;
        accs[wave * 256 + lane + 128] = c2;
        if (lane < 8) accs[wave * 256 + lane + 192] = c3;
        __syncthreads();
        mpart[(size_t)tid * 256 + sb] =
            accs[tid] + accs[256 + tid] + accs[512 + tid] + accs[768 + tid];
        return;
    }
    // ---- normalize: 512 blocks x 8 rows, one wave per row, no barriers ----
    {
        int nb = blockIdx.x - 768;           // 0..511
        int lane = tid & 63, wave = tid >> 6;
        #pragma unroll
        for (int rr = 0; rr < 2; rr++) {
            int row = nb * 8 + rr * 4 + wave;
            const float* zr = z    + (size_t)row * D_N;
            const float* br = base + (size_t)row * D_N;
            float4 zv0 = *(const float4*)(zr + (size_t)lane * 4);
            float4 zv1 = *(const float4*)(zr + (size_t)(lane + 64) * 4);
            float4 zv2 = *(const float4*)(zr + (size_t)(lane + 128) * 4);
            float4 bv0 = *(const float4*)(br + (size_t)lane * 4);
            float4 bv1 = *(const float4*)(br + (size_t)(lane + 64) * 4);
            float4 bv2 = *(const float4*)(br + (size_t)(lane + 128) * 4);
            float s1 = zv0.x*zv0.x + zv0.y*zv0.y + zv0.z*zv0.z + zv0.w*zv0.w
                     + zv1.x*zv1.x + zv1.y*zv1.y + zv1.z*zv1.z + zv1.w*zv1.w
                     + zv2.x*zv2.x + zv2.y*zv2.y + zv2.z*zv2.z + zv2.w*zv2.w;
            float s2 = bv0.x*bv0.x + bv0.y*bv0.y + bv0.z*bv0.z + bv0.w*bv0.w
                     + bv1.x*bv1.x + bv1.y*bv1.y + bv1.z*bv1.z + bv1.w*bv1.w
                     + bv2.x*bv2.x + bv2.y*bv2.y + bv2.z*bv2.z + bv2.w*bv2.w;
            #pragma unroll
            for (int m = 32; m > 0; m >>= 1) {
                s1 += __shfl_xor(s1, m);
                s2 += __shfl_xor(s2, m);
            }
            float sc1 = 16.0f / fmaxf(sqrtf(s1), 1e-12f);
            float sc2 = 16.0f / fmaxf(sqrtf(s2), 1e-12f);
            size_t o = (size_t)row * D_N;
            int sw8 = ((row >> 3) & 1) << 3;         // half-swap key
            *(unsigned int*)(zn8 + o + (((lane      ) * 4) ^ sw8)) =
                pack4fp8(zv0.x*sc1, zv0.y*sc1, zv0.z*sc1, zv0.w*sc1);
            *(unsigned int*)(zn8 + o + (((lane +  64) * 4) ^ sw8)) =
                pack4fp8(zv1.x*sc1, zv1.y*sc1, zv1.z*sc1, zv1.w*sc1);
            *(unsigned int*)(zn8 + o + (((lane + 128) * 4) ^ sw8)) =
                pack4fp8(zv2.x*sc1, zv2.y*sc1, zv2.z*sc1, zv2.w*sc1);
            *(unsigned int*)(bn8 + o + (((lane      ) * 4) ^ sw8)) =
                pack4fp8(bv0.x*sc2, bv0.y*sc2, bv0.z*sc2, bv0.w*sc2);
            *(unsigned int*)(bn8 + o + (((lane +  64) * 4) ^ sw8)) =
                pack4fp8(bv1.x*sc2, bv1.y*sc2, bv1.z*sc2, bv1.w*sc2);
            *(unsigned int*)(bn8 + o + (((lane + 128) * 4) ^ sw8)) =
                pack4fp8(bv2.x*sc2, bv2.y*sc2, bv2.z*sc2, bv2.w*sc2);
        }
    }
}

// ---------------------------------------------------------------------------
// Kernel 2: triangular contrastive main, fp8. 512 persistent blocks pull
// 1056 jobs (992 half-pairs, then 64 half-diags) from an atomic queue.
// Half-pair job (pp, h): rows A = ib*128+h*64+[0,64), cols C = jc*128+[0,128).
//   MS(A,C) once; attn1 = f1z[A].f2z[C]^T -> orient-1 (rows in A);
//   attn2T = f2z[A].f1z[C]^T -> orient-2 (rows in C, column reduction).
// Half-diag job: same geometry with ib==jc, orient-1 only, r==c excluded.
// ---------------------------------------------------------------------------
__global__ __launch_bounds__(256, 2) void main_fused(
    const unsigned char* __restrict__ zn8, const unsigned char* __restrict__ bn8,
    const unsigned char* __restrict__ f1z8, const unsigned char* __restrict__ f2z8,
    float* __restrict__ partials, int* __restrict__ jobcnt)
{
    __shared__ __align__(16) unsigned char S[53248];   // 52 KB
    __shared__ int sh_j;
    // MS phase:   SA_B 0 (8K) | SA_S 8K (8K) | SB_B 16K (16K) | SB_S 32K (16K)
    // attn phase: F1 0 (16K, 64 rows) | F2 16K (32K, 128 rows) | red 48K (4K)
    unsigned char* SA_B = S;
    unsigned char* SA_S = S + 8192;
    unsigned char* SB_B = S + 16384;
    unsigned char* SB_S = S + 32768;
    unsigned char* F1   = S;
    unsigned char* F2   = S + 16384;
    float4* red = (float4*)(S + 49152);                // [2][128]

    int tid = threadIdx.x, lane = tid & 63, wave = tid >> 6;
    int quad = lane >> 4, col = lane & 15;
    int wr3 = wave >> 1, wc3 = wave & 1;               // 32-row / 64-col halves
    const int r8 = lane >> 3;
    const int kbl8 = (lane & 7) ^ r8;                  // MS staging granule swizzle
    const int sub8 = ((quad & 1) ^ (col >> 3)) << 3;   // half-swap sub-slot

    for (;;) {
        __syncthreads();                               // LDS + sh_j reuse guard
        if (tid == 0) sh_j = atomicAdd(jobcnt, 1);
        __syncthreads();
        unsigned int j = (unsigned int)sh_j;           // garbage/negative -> huge
        if (j >= NJOBS) return;

        int ib, jc, h; bool diag;
        if (j < 992u) {
            int pp = (int)(j >> 1); h = (int)(j & 1u); diag = false;
            int t = (int)((1.0f + sqrtf(8.0f * (float)pp + 1.0f)) * 0.5f);
            t = (t < 1) ? 1 : ((t > 31) ? 31 : t);     // clamp before adjust
            while (t > 1  && t * (t - 1) / 2 > pp) --t;
            while (t < 31 && (t + 1) * t / 2 <= pp) ++t;
            jc = t; ib = pp - t * (t - 1) / 2;         // 0 <= ib < jc < 32
        } else {
            int dd = (int)(j - 992u); ib = jc = dd >> 1; h = dd & 1; diag = true;
        }
        int aRow0 = ib * 128 + h * 64;                 // A panel (64 rows)
        int bRow0 = jc * 128;                          // C panel (128 rows)

        // ===== MS: mask (bn8) + sim (zn8), 64x128, K=768 in 6 chunks =====
        v4f accB[2][4], accS[2][4];
        ZERO_ACC24(accB); ZERO_ACC24(accS);
        for (int kc = 0; kc < D_N; kc += 128) {
            __syncthreads();
            #pragma unroll
            for (int s = 0; s < 4; s++) {
                int rowbase = s * 32 + wave * 8;
                size_t gOff = (size_t)(bRow0 + rowbase + r8) * D_N + kc + kbl8 * 16;
                gld16c(bn8 + gOff, SB_B + rowbase * 128);
                gld16c(zn8 + gOff, SB_S + rowbase * 128);
            }
            if (!diag) {
                #pragma unroll
                for (int s = 0; s < 2; s++) {
                    int rowbase = s * 32 + wave * 8;
                    size_t gOff = (size_t)(aRow0 + rowbase + r8) * D_N + kc + kbl8 * 16;
                    gld16c(bn8 + gOff, SA_B + rowbase * 128);
                    gld16c(zn8 + gOff, SA_S + rowbase * 128);
                }
            }
            __syncthreads();
            const unsigned char* AB = diag ? (SB_B + h * 64 * 128) : SA_B;
            const unsigned char* AS = diag ? (SB_S + h * 64 * 128) : SA_S;
            #pragma unroll
            for (int kk = 0; kk < 4; kk++) {
                int gbase = kk * 2 + (quad >> 1);
                int off = ((gbase ^ (col & 7)) << 4) + sub8;
                long a1[2], a2[2], b1[4], b2[4];
                #pragma unroll
                for (int t = 0; t < 2; t++) {
                    int rA = (wr3 * 32 + t * 16 + col) * 128;
                    a1[t] = *(const long*)(AB + rA + off);
                    a2[t] = *(const long*)(AS + rA + off);
                }
                #pragma unroll
                for (int t = 0; t < 4; t++) {
                    int rB = (wc3 * 64 + t * 16 + col) * 128;
                    b1[t] = *(const long*)(SB_B + rB + off);
                    b2[t] = *(const long*)(SB_S + rB + off);
                }
                #pragma unroll
                for (int tr = 0; tr < 2; tr++)
                    #pragma unroll
                    for (int tc = 0; tc < 4; tc++) {
                        accB[tr][tc] = __builtin_amdgcn_mfma_f32_16x16x32_fp8_fp8(
                            a1[tr], b1[tc], accB[tr][tc], 0, 0, 0);
                        accS[tr][tc] = __builtin_amdgcn_mfma_f32_16x16x32_fp8_fp8(
                            a2[tr], b2[tc], accS[tr][tc], 0, 0, 0);
                    }
            }
        }

        // ===== issue attn pass-1 staging; mask extraction overlaps DMA =====
        __syncthreads();                  // MS LDS reads complete
        {
            int r4 = lane >> 4;
            #pragma unroll
            for (int s = 0; s < 8; s++) {
                int rowbase = s * 16 + wave * 4;
                int row = rowbase + r4;                        // 0..127
                int kb = (lane & 15) ^ (row & 15);
                gld16c(f2z8 + (size_t)(bRow0 + row) * HID_N + kb * 16, F2 + rowbase * 256);
            }
            #pragma unroll
            for (int s = 0; s < 4; s++) {
                int rowbase = s * 16 + wave * 4;
                int row = rowbase + r4;                        // 0..63
                int kb = (lane & 15) ^ (row & 15);
                gld16c(f1z8 + (size_t)(aRow0 + row) * HID_N + kb * 16, F1 + rowbase * 256);
            }
        }

        // mask bits from accB (scale 16x16=256: threshold 0.05*256 = 12.8)
        unsigned int mb = 0u;
        #pragma unroll
        for (int tr = 0; tr < 2; tr++)
            #pragma unroll
            for (int tc = 0; tc < 4; tc++)
                #pragma unroll
                for (int reg = 0; reg < 4; reg++) {
                    int grow = aRow0 + wr3 * 32 + tr * 16 + quad * 4 + reg;
                    int gcol = bRow0 + wc3 * 64 + tc * 16 + col;
                    if (accB[tr][tc][reg] > 12.8f && grow != gcol)
                        mb |= 1u << (tr * 16 + tc * 4 + reg);
                }

        // ===== attn pass 1: f1z[A] . f2z[C]^T, K=256 fully staged =====
        v4f accA[2][4]; ZERO_ACC24(accA);
        __syncthreads();                  // DMA drained
        #pragma unroll
        for (int kk = 0; kk < 8; kk++) {
            int gbase = kk * 2 + (quad >> 1);
            int off = ((gbase ^ col) << 4) + sub8;
            long af[2], bf[4];
            #pragma unroll
            for (int t = 0; t < 2; t++)
                af[t] = *(const long*)(F1 + (wr3 * 32 + t * 16 + col) * 256 + off);
            #pragma unroll
            for (int t = 0; t < 4; t++)
                bf[t] = *(const long*)(F2 + (wc3 * 64 + t * 16 + col) * 256 + off);
            #pragma unroll
            for (int tr = 0; tr < 2; tr++)
                #pragma unroll
                for (int tc = 0; tc < 4; tc++)
                    accA[tr][tc] = __builtin_amdgcn_mfma_f32_16x16x32_fp8_fp8(
                        af[tr], bf[tc], accA[tr][tc], 0, 0, 0);
        }

        // all waves done with F1/F2 -> restage for pass 2 (pairs only)
        __syncthreads();
        if (!diag) {
            int r4 = lane >> 4;
            #pragma unroll
            for (int s = 0; s < 8; s++) {
                int rowbase = s * 16 + wave * 4;
                int row = rowbase + r4;
                int kb = (lane & 15) ^ (row & 15);
                gld16c(f1z8 + (size_t)(bRow0 + row) * HID_N + kb * 16, F2 + rowbase * 256);
            }
            #pragma unroll
            for (int s = 0; s < 4; s++) {
                int rowbase = s * 16 + wave * 4;
                int row = rowbase + r4;
                int kb = (lane & 15) ^ (row & 15);
                gld16c(f2z8 + (size_t)(aRow0 + row) * HID_N + kb * 16, F1 + rowbase * 256);
            }
        }

        // ===== combine orient-1 (rows in A), streaming per tr; overlaps DMA
        #pragma unroll
        for (int tr = 0; tr < 2; tr++) {
            float ls[4], as[4], nn[4], ds[4];
            #pragma unroll
            for (int r = 0; r < 4; r++) { ls[r]=0.f; as[r]=0.f; nn[r]=0.f; ds[r]=0.f; }
            #pragma unroll
            for (int tc = 0; tc < 4; tc++)
                #pragma unroll
                for (int reg = 0; reg < 4; reg++) {
                    float sv = accS[tr][tc][reg] * 0.00390625f;
                    int grow = aRow0 + wr3 * 32 + tr * 16 + quad * 4 + reg;
                    int gcol = bRow0 + wc3 * 64 + tc * 16 + col;
                    if (grow != gcol) ds[reg] += __expf(sv * 10.0f);
                    if ((mb >> (tr * 16 + tc * 4 + reg)) & 1u) {
                        float e = __expf(accA[tr][tc][reg] * 0.0625f);
                        ls[reg] += e; as[reg] += e * sv; nn[reg] += 1.f;
                    }
                }
            #pragma unroll
            for (int r = 0; r < 4; r++) {
                #pragma unroll
                for (int m = 1; m < 16; m <<= 1) {
                    ls[r] += __shfl_xor(ls[r], m);
                    as[r] += __shfl_xor(as[r], m);
                    ds[r] += __shfl_xor(ds[r], m);
                    nn[r] += __shfl_xor(nn[r], m);
                }
                if (col == 0) {
                    int row = aRow0 + wr3 * 32 + tr * 16 + quad * 4 + r;
                    float4 v; v.x = ls[r]; v.y = as[r]; v.z = ds[r]; v.w = nn[r];
                    *(float4*)(partials + ((size_t)row * 64 + jc * 2 + wc3) * 4) = v;
                }
            }
        }

        // ===== attn pass 2 + combine orient-2 (rows in C), pairs only =====
        if (!diag) {
            ZERO_ACC24(accA);
            __syncthreads();              // pass-2 DMA drained
            #pragma unroll
            for (int kk = 0; kk < 8; kk++) {
                int gbase = kk * 2 + (quad >> 1);
                int off = ((gbase ^ col) << 4) + sub8;
                long af[2], bf[4];
                #pragma unroll
                for (int t = 0; t < 2; t++)
                    af[t] = *(const long*)(F1 + (wr3 * 32 + t * 16 + col) * 256 + off);
                #pragma unroll
                for (int t = 0; t < 4; t++)
                    bf[t] = *(const long*)(F2 + (wc3 * 64 + t * 16 + col) * 256 + off);
                #pragma unroll
                for (int tr = 0; tr < 2; tr++)
                    #pragma unroll
                    for (int tc = 0; tc < 4; tc++)
                        accA[tr][tc] = __builtin_amdgcn_mfma_f32_16x16x32_fp8_fp8(
                            af[tr], bf[tc], accA[tr][tc], 0, 0, 0);
            }
            // accA[tr][tc][reg] = f2z[aRow0+lr].f1z[bRow0+lc] = attn[lc][lr]:
            // output row = bRow0+lc, summation over lr -> column reduction.
            #pragma unroll
            for (int tc = 0; tc < 4; tc++) {
                float l2 = 0.f, a2 = 0.f, d2 = 0.f, n2 = 0.f;
                #pragma unroll
                for (int tr = 0; tr < 2; tr++)
                    #pragma unroll
                    for (int reg = 0; reg < 4; reg++) {
                        float sv = accS[tr][tc][reg] * 0.00390625f;
                        d2 += __expf(sv * 10.0f);
                        if ((mb >> (tr * 16 + tc * 4 + reg)) & 1u) {
                            float e = __expf(accA[tr][tc][reg] * 0.0625f);
                            l2 += e; a2 += e * sv; n2 += 1.f;
                        }
                    }
                #pragma unroll
                for (int m = 16; m < 64; m <<= 1) {
                    l2 += __shfl_xor(l2, m);
                    a2 += __shfl_xor(a2, m);
                    d2 += __shfl_xor(d2, m);
                    n2 += __shfl_xor(n2, m);
                }
                if (lane < 16) {
                    float4 v; v.x = l2; v.y = a2; v.z = d2; v.w = n2;
                    red[wr3 * 128 + wc3 * 64 + tc * 16 + lane] = v;
                }
            }
            __syncthreads();              // red complete
            if (tid < 128) {
                float4 u = red[tid], v = red[128 + tid];
                float4 w; w.x = u.x + v.x; w.y = u.y + v.y;
                w.z = u.z + v.z; w.w = u.w + v.w;
                *(float4*)(partials + ((size_t)(bRow0 + tid) * 64 + ib * 2 + h) * 4) = w;
            }
        }
    }
}

// ---------------------------------------------------------------------------
// Kernel 3: reduce per-row partials; last block does entropy + combine.
// ---------------------------------------------------------------------------
__global__ __launch_bounds__(256) void row_reduce_fin(
    const float* __restrict__ partials, const float* __restrict__ mpart,
    float* __restrict__ acc, float* __restrict__ out)
{
    int tid = threadIdx.x;
    int row = blockIdx.x * 64 + (tid >> 2);
    int sub = tid & 3;
    const float4* p = (const float4*)partials + (size_t)row * 64 + sub * 16;
    float L = 0.f, A = 0.f, Dn = 0.f, NN = 0.f;
    #pragma unroll
    for (int c = 0; c < 16; c++) { float4 v = p[c]; L += v.x; A += v.y; Dn += v.z; NN += v.w; }
    #pragma unroll
    for (int m = 1; m < 4; m <<= 1) {
        L += __shfl_xor(L, m); A += __shfl_xor(A, m);
        Dn += __shfl_xor(Dn, m); NN += __shfl_xor(NN, m);
    }
    float per = 0.f, val = 0.f;
    if (sub == 0 && NN > 0.5f) {
        per = (logf(Dn + 1e-8f) - 10.0f * (A / L)) / NN;
        val = 1.0f;
    }
    __shared__ float red[256];
    __shared__ float r2s[256];
    __shared__ int amLast;
    red[tid] = per; r2s[tid] = val; __syncthreads();
    for (int s = 128; s > 0; s >>= 1) {
        if (tid < s) { red[tid] += red[tid + s]; r2s[tid] += r2s[tid + s]; }
        __syncthreads();
    }
    if (tid == 0) {
        atomicAdd(&acc[0], red[0]);
        atomicAdd(&acc[1], r2s[0]);
        __threadfence();
        int old = atomicAdd((int*)&acc[2], 1);
        amLast = (old == (int)gridDim.x - 1);
    }
    __syncthreads();
    if (!amLast) return;

    __shared__ float bcast[2];
    float pcl = 0.0f;
    if (tid < NCLS) {
        const float4* mp = (const float4*)(mpart + (size_t)tid * 256);
        float s = 0.f;
        #pragma unroll
        for (int c = 0; c < 64; c++) { float4 v = mp[c]; s += v.x + v.y + v.z + v.w; }
        pcl = s * (1.0f / 4096.0f);
    }
    red[tid] = (tid < 100) ? pcl : 0.0f; __syncthreads();
    for (int s = 128; s > 0; s >>= 1) { if (tid < s) red[tid] += red[tid + s]; __syncthreads(); }
    if (tid == 0) bcast[0] = red[0];
    __syncthreads();
    red[tid] = (tid >= 100 && tid < NCLS) ? pcl : 0.0f; __syncthreads();
    for (int s = 128; s > 0; s >>= 1) { if (tid < s) red[tid] += red[tid + s]; __syncthreads(); }
    if (tid == 0) bcast[1] = red[0];
    __syncthreads();
    float p_old = bcast[0], p_new = bcast[1];

    float t = 0.0f;
    if (tid < 100)       { float q = pcl / (p_old + 1e-8f); t = q * logf(q + 1e-8f); }
    else if (tid < NCLS) { float q = pcl / (p_new + 1e-8f); t = q * logf(q + 1e-8f); }
    red[tid] = t; __syncthreads();
    for (int s = 128; s > 0; s >>= 1) { if (tid < s) red[tid] += red[tid + s]; __syncthreads(); }

    if (tid == 0) {
        float s0 = __hip_atomic_load(&acc[0], __ATOMIC_RELAXED, __HIP_MEMORY_SCOPE_AGENT);
        float s1 = __hip_atomic_load(&acc[1], __ATOMIC_RELAXED, __HIP_MEMORY_SCOPE_AGENT);
        float loss_inter = p_old * logf(p_old + 1e-8f) + p_new * logf(p_new + 1e-8f)
                           + 0.69314718056f;
        float loss_entropy = loss_inter + red[0] + 2.0f * 4.60517018599f;
        float lc = (s1 > 0.5f) ? s0 / s1 : 0.0f;
        out[0] = loss_entropy + lc;
    }
}

// ---------------------------------------------------------------------------
extern "C" void kernel_launch(void* const* d_in, const int* in_sizes, int n_in,
                              void* d_out, int out_size, void* d_ws, size_t ws_size,
                              hipStream_t stream)
{
    const float* z_u    = (const float*)d_in[0];
    const float* logits = (const float*)d_in[1];
    const int*   oldi   = (const int*)d_in[2];
    const int*   newi   = (const int*)d_in[3];
    const float* basef  = (const float*)d_in[4];
    const float* f1w    = (const float*)d_in[5];
    const float* f1b    = (const float*)d_in[6];
    const float* f2w    = (const float*)d_in[7];
    const float* f2b    = (const float*)d_in[8];
    float* out = (float*)d_out;

    unsigned char* zn8   = (unsigned char*)d_ws;           // [B][D] fp8
    unsigned char* bn8   = zn8 + (size_t)B_N * D_N;
    unsigned char* f1z8  = bn8 + (size_t)B_N * D_N;        // [B][HID] fp8
    unsigned char* f2z8  = f1z8 + (size_t)B_N * HID_N;
    float* partials = (float*)(f2z8 + (size_t)B_N * HID_N); // [B][64][4]
    float* mpart    = partials + (size_t)B_N * 64 * 4;      // [256 class][256 blk]
    float* accums   = mpart + 256 * 256;                    // [0..3] + jobcnt [4]
    int*   jobcnt   = (int*)(accums + 4);

    pre_all<<<512 + 256 + 512, 256, 0, stream>>>(
        z_u, basef, f1w, f2w, f1b, f2b, logits, oldi, newi,
        zn8, bn8, f1z8, f2z8, mpart, accums);
    main_fused<<<512, 256, 0, stream>>>(zn8, bn8, f1z8, f2z8, partials, jobcnt);
    row_reduce_fin<<<64, 256, 0, stream>>>(partials, mpart, accums, out);
}